// Round 6
// baseline (765.786 us; speedup 1.0000x reference)
//
#include <hip/hip_runtime.h>

// Overdamped Langevin (OU), bit-matching JAX partitionable threefry RNG.
// base key (0,42); step key_j = threefry((0,42),(0,j)); per element f at step j:
// bits = b0^b1 of threefry(key_j,(0,f)); u in (-1,1); z = sqrt2*erfinv(u) (Giles);
// x <- x - (dt/g) x + sqrt(2 kT dt/g) z.  Frame 0 = x0, frame c = after c*store_every.
//
// R6: the 20-round threefry hash is INLINE ASM (exactly 73 VALU ops/step:
// 2 init + 20x{add,alignbit,xor} + 10 injection adds + final xor). Per-step
// injection constants (ks2+1, k0+2, k1+3, ks2+4, k0+5) are precomputed in an
// expanded __constant__ table so the asm needs no SALU. Float transform is
// bit-identical to R5 (passed, absmax 0.015625).

#define KCAP 1024  // compile-time key slots (harness n_steps = 1000)

// ---------- compile-time key table ----------
// 12 words/step (48B): s=k0+k1, b=k1, c=ks2, a=k0, c1=ks2+1, a2=k0+2,
//                      b3=k1+3, c4=ks2+4, a5=k0+5, pad x3
struct alignas(16) Rec { unsigned s, b, c, a, c1, a2, b3, c4, a5, p0, p1, p2; };
struct KTable { Rec r[KCAP]; };

constexpr unsigned crotl(unsigned v, int r) { return (v << r) | (v >> (32 - r)); }

constexpr KTable gen_keys() {
    KTable t{};
    for (unsigned j = 0; j < KCAP; ++j) {
        const unsigned k0 = 0u, k1 = 42u, ks2 = k0 ^ k1 ^ 0x1BD11BDAu;
        unsigned x0 = 0u + k0, x1 = j + k1;
        const int rots[20] = {13,15,26,6, 17,29,16,24, 13,15,26,6, 17,29,16,24, 13,15,26,6};
        int ri = 0;
        for (int blk = 0; blk < 5; ++blk) {
            for (int rr = 0; rr < 4; ++rr) { x0 += x1; x1 = crotl(x1, rots[ri++]); x1 ^= x0; }
            switch (blk) {
                case 0: x0 += k1;  x1 += ks2 + 1u; break;
                case 1: x0 += ks2; x1 += k0 + 2u;  break;
                case 2: x0 += k0;  x1 += k1 + 3u;  break;
                case 3: x0 += k1;  x1 += ks2 + 4u; break;
                case 4: x0 += ks2; x1 += k0 + 5u;  break;
            }
        }
        const unsigned b0 = x0, b1 = x1;
        const unsigned K0 = b0, K1 = b1, KS2 = b0 ^ b1 ^ 0x1BD11BDAu;
        t.r[j] = Rec{K0 + K1, K1, KS2, K0,
                     KS2 + 1u, K0 + 2u, K1 + 3u, KS2 + 4u, K0 + 5u, 0u, 0u, 0u};
    }
    return t;
}

__constant__ KTable KTAB = gen_keys();

// ---------- exact-count threefry hash (73 VALU ops) ----------
// rotl(x,r) == v_alignbit_b32 x,x,x,(32-r); shifts: 13->19 15->17 26->6 6->26
//                                                    17->15 29->3 16->16 24->8
__device__ __forceinline__ unsigned tf_bits(unsigned t, const Rec& k) {
    unsigned x0, x1;
#define R3(sh) \
    "v_add_u32 %[x0], %[x0], %[x1]\n\t" \
    "v_alignbit_b32 %[x1], %[x1], %[x1], " #sh "\n\t" \
    "v_xor_b32 %[x1], %[x1], %[x0]\n\t"
    asm(
        // round 1 (init folded: x0=(k0+k1)+t, x1=rotl(k1+t,13)^x0)
        "v_add_u32 %[x1], %[kb], %[tt]\n\t"
        "v_add_u32 %[x0], %[ks], %[tt]\n\t"
        "v_alignbit_b32 %[x1], %[x1], %[x1], 19\n\t"
        "v_xor_b32 %[x1], %[x1], %[x0]\n\t"
        R3(17) R3(6) R3(26)                 // rounds 2-4
        "v_add_u32 %[x0], %[kb], %[x0]\n\t" // inject 1: x0+=k1, x1+=ks2+1
        "v_add_u32 %[x1], %[c1], %[x1]\n\t"
        R3(15) R3(3) R3(16) R3(8)           // rounds 5-8
        "v_add_u32 %[x0], %[kc], %[x0]\n\t" // inject 2: x0+=ks2, x1+=k0+2
        "v_add_u32 %[x1], %[a2], %[x1]\n\t"
        R3(19) R3(17) R3(6) R3(26)          // rounds 9-12
        "v_add_u32 %[x0], %[ka], %[x0]\n\t" // inject 3: x0+=k0, x1+=k1+3
        "v_add_u32 %[x1], %[b3], %[x1]\n\t"
        R3(15) R3(3) R3(16) R3(8)           // rounds 13-16
        "v_add_u32 %[x0], %[kb], %[x0]\n\t" // inject 4: x0+=k1, x1+=ks2+4
        "v_add_u32 %[x1], %[c4], %[x1]\n\t"
        R3(19) R3(17) R3(6) R3(26)          // rounds 17-20
        "v_add_u32 %[x0], %[kc], %[x0]\n\t" // inject 5: x0+=ks2, x1+=k0+5
        "v_add_u32 %[x1], %[a5], %[x1]\n\t"
        "v_xor_b32 %[x0], %[x0], %[x1]\n\t" // bits = b0 ^ b1
        : [x0]"=&v"(x0), [x1]"=&v"(x1)
        : [tt]"v"(t), [ks]"s"(k.s), [kb]"s"(k.b), [kc]"s"(k.c), [ka]"s"(k.a),
          [c1]"s"(k.c1), [a2]"s"(k.a2), [b3]"s"(k.b3), [c4]"s"(k.c4), [a5]"s"(k.a5));
#undef R3
    return x0;
}

// ---------- float transform (bit-identical to R5) ----------
#if __has_builtin(__builtin_amdgcn_alignbit)
#define SPLICE(bits) __builtin_amdgcn_alignbit(0x7Fu, (bits), 9u)  // (bits>>9)|0x3f800000
#else
#define SPLICE(bits) (((bits) >> 9) | 0x3f800000u)
#endif

struct Consts {
    float P0, P1, P2, P3, P4, P5, P6, P7, P8;   // Giles lo-branch poly
    float NLN2, M25, M3, LO;                    // -ln2, -2.5, -3.0, nextafter(-1,0)
};

__device__ __forceinline__ float poly_lo(float w, const Consts& cc) {
    float p = cc.P0;
    p = fmaf(p, w, cc.P1);
    p = fmaf(p, w, cc.P2);
    p = fmaf(p, w, cc.P3);
    p = fmaf(p, w, cc.P4);
    p = fmaf(p, w, cc.P5);
    p = fmaf(p, w, cc.P6);
    p = fmaf(p, w, cc.P7);
    p = fmaf(p, w, cc.P8);
    return p;
}
__device__ __forceinline__ float poly_hi(float s) {   // rare path
    float p =       -0.000200214257f;
    p = fmaf(p, s,   0.000100950558f);
    p = fmaf(p, s,   0.00134934322f);
    p = fmaf(p, s,  -0.00367342844f);
    p = fmaf(p, s,   0.00573950773f);
    p = fmaf(p, s,  -0.0076224613f);
    p = fmaf(p, s,   0.00943887047f);
    p = fmaf(p, s,   1.00167406f);
    p = fmaf(p, s,   2.83297682f);
    return p;
}

__device__ __forceinline__ float normal_of_bits(unsigned bits, const Consts& cc) {
    float F = __uint_as_float(SPLICE(bits));            // [1,2)
    float u = fmaf(F, 2.0f, cc.M3);                     // == 2(F-1)+LO (+2^-24)
    u = fmaxf(u, cc.LO);
    float h = fmaf(-u, u, 1.0f);                        // 1 - u^2
    float l2 = __log2f(h);                              // v_log_f32
    float p;
    if (__builtin_expect(__any(l2 <= -7.2134752f), 0)) {   // any lane: w >= 5
        float w  = l2 * cc.NLN2;
        float p1 = poly_lo(w + cc.M25, cc);
        float p2 = poly_hi(sqrtf(w) + cc.M3);
        p = (l2 > -7.2134752f) ? p1 : p2;
    } else {
        p = poly_lo(fmaf(l2, cc.NLN2, cc.M25), cc);     // w - 2.5 in one fma
    }
    return p * u;
}

// generic fallback: on-the-fly key expansion (s >= KCAP)
__device__ __forceinline__ Rec make_key(unsigned j) {
    const unsigned k0 = 0u, k1 = 42u, ks2 = k0 ^ k1 ^ 0x1BD11BDAu;
    unsigned x0 = k0, x1 = j + k1;
#define RND(r) { x0 += x1; x1 = __builtin_rotateleft32(x1, r) ^ x0; }
    RND(13) RND(15) RND(26) RND(6)
    x0 += k1;  x1 += ks2 + 1u;
    RND(17) RND(29) RND(16) RND(24)
    x0 += ks2; x1 += k0 + 2u;
    RND(13) RND(15) RND(26) RND(6)
    x0 += k0;  x1 += k1 + 3u;
    RND(17) RND(29) RND(16) RND(24)
    x0 += k1;  x1 += ks2 + 4u;
    RND(13) RND(15) RND(26) RND(6)
    x0 += ks2; x1 += k0 + 5u;
#undef RND
    const unsigned K0 = x0, K1 = x1, KS2 = x0 ^ x1 ^ 0x1BD11BDAu;
    return Rec{K0 + K1, K1, KS2, K0, KS2 + 1u, K0 + 2u, K1 + 3u, KS2 + 4u, K0 + 5u,
               0u, 0u, 0u};
}

__global__ __launch_bounds__(256) void OverdampedLangevin_62362925138458_kernel(
    const float* __restrict__ x0p,
    const float* __restrict__ gamma_p,
    const float* __restrict__ kT_p,
    const float* __restrict__ dt_p,
    const int*   __restrict__ nsteps_p,
    const int*   __restrict__ store_p,
    float*       __restrict__ out,
    int E)
{
    const int n_steps = *nsteps_p;
    const int store_every = *store_p;

    const unsigned t = blockIdx.x * blockDim.x + threadIdx.x;
    if ((int)t >= E) return;

    const float g  = gamma_p[0];
    const float kT = kT_p[0];
    const float dt = dt_p[0];
    float scale2 = sqrtf(2.0f * kT * dt / g) * 1.41421356f;
    float na = -(dt / g);

    Consts cc{2.81022636e-08f,  3.43273939e-07f, -3.5233877e-06f,
             -4.39150654e-06f,  0.00021858087f,  -0.00125372503f,
             -0.00417768164f,   0.246640727f,     1.50140941f,
             -0.69314718f,     -2.5f,            -3.0f, -0.99999994f};
    asm("" : "+v"(cc.P0), "+v"(cc.P1), "+v"(cc.P2), "+v"(cc.P3), "+v"(cc.P4),
             "+v"(cc.P5), "+v"(cc.P6), "+v"(cc.P7), "+v"(cc.P8),
             "+v"(cc.NLN2), "+v"(cc.M25), "+v"(cc.M3), "+v"(cc.LO),
             "+v"(scale2), "+v"(na));

    float x = x0p[t];
    out[t] = x;                                  // frame 0

    if (store_every == 10 && n_steps % 10 == 0 && n_steps <= KCAP) {
        const int nc = n_steps / 10;
        float* op = out + (size_t)E + t;
        int idx = 0;
        for (int c = 0; c < nc; ++c) {
#pragma unroll
            for (int s = 0; s < 10; ++s) {
                unsigned bits = tf_bits(t, KTAB.r[idx + s]);
                float z = normal_of_bits(bits, cc);
                x = fmaf(scale2, z, fmaf(na, x, x));
            }
            idx += 10;
            *op = x;
            op += (size_t)E;
        }
    } else {
        int frame = 1, since = 0;
#pragma unroll 1
        for (int s = 0; s < n_steps; ++s) {
            Rec k = (s < KCAP) ? KTAB.r[s] : make_key((unsigned)s);
            unsigned bits = tf_bits(t, k);
            float z = normal_of_bits(bits, cc);
            x = fmaf(scale2, z, fmaf(na, x, x));
            if (++since == store_every) {
                since = 0;
                out[(size_t)frame * (size_t)E + t] = x;
                ++frame;
            }
        }
    }
}

extern "C" void kernel_launch(void* const* d_in, const int* in_sizes, int n_in,
                              void* d_out, int out_size, void* d_ws, size_t ws_size,
                              hipStream_t stream) {
    const float* x0    = (const float*)d_in[0];
    const float* gam   = (const float*)d_in[1];
    const float* kT    = (const float*)d_in[2];
    const float* dt    = (const float*)d_in[3];
    const int*   nst   = (const int*)d_in[4];
    const int*   sev   = (const int*)d_in[5];
    float*       out   = (float*)d_out;

    const int E = in_sizes[0];                 // 100000 * 3 = 300000
    const int blocks = (E + 255) / 256;
    OverdampedLangevin_62362925138458_kernel<<<blocks, 256, 0, stream>>>(
        x0, gam, kT, dt, nst, sev, out, E);
}

// Round 7
// 657.981 us; speedup vs baseline: 1.1638x; 1.1638x over previous
//
#include <hip/hip_runtime.h>

// Overdamped Langevin (OU), bit-matching JAX partitionable threefry RNG.
// base key (0,42); step key_j = threefry((0,42),(0,j)); per element e at step j:
// bits = b0^b1 of threefry(key_j,(0,e)); u in (-1,1); z = sqrt2*erfinv(u) (Giles);
// x <- x - (dt/g) x + sqrt(2 kT dt/g) z.  Frame 0 = x0, frame c = after c*store_every.
//
// R7 structure (issue-bound => attack wave imbalance: 4688 waves/1024 SIMDs = 4.58,
// busiest SIMD 5 => 8.4% structural loss in the serial-per-element form):
//   Linear recurrence => per 10-step chunk, noise sum S_c = sum_s w_s*z_s is
//   x-independent (w_s = scale2*a^(9-s), wave-uniform).
//   K1: items (element, chunk-pair) on a 2D grid -> HW-balanced, writes S_c into out.
//   K2: per-element scan x = hom10(x) + S_c, in-place in out (streaming, ~40us).
//   KG: generic R5 serial kernel, self-enabled iff the fast config doesn't hold.
// Hash + transform are BIT-IDENTICAL to R5 (passed, absmax 0.015625).

#define KCAP 1024  // compile-time key slots (harness n_steps = 1000)

// ---------- compile-time key table ----------
struct alignas(16) Rec { unsigned s, b, c, a; };  // s=k0+k1, b=k1, c=ks2, a=k0
struct KTable { Rec r[KCAP]; };

constexpr unsigned crotl(unsigned v, int r) { return (v << r) | (v >> (32 - r)); }

constexpr KTable gen_keys() {
    KTable t{};
    for (unsigned j = 0; j < KCAP; ++j) {
        const unsigned k0 = 0u, k1 = 42u, ks2 = k0 ^ k1 ^ 0x1BD11BDAu;
        unsigned x0 = 0u + k0, x1 = j + k1;
        const int rots[20] = {13,15,26,6, 17,29,16,24, 13,15,26,6, 17,29,16,24, 13,15,26,6};
        int ri = 0;
        for (int blk = 0; blk < 5; ++blk) {
            for (int rr = 0; rr < 4; ++rr) { x0 += x1; x1 = crotl(x1, rots[ri++]); x1 ^= x0; }
            switch (blk) {
                case 0: x0 += k1;  x1 += ks2 + 1u; break;
                case 1: x0 += ks2; x1 += k0 + 2u;  break;
                case 2: x0 += k0;  x1 += k1 + 3u;  break;
                case 3: x0 += k1;  x1 += ks2 + 4u; break;
                case 4: x0 += ks2; x1 += k0 + 5u;  break;
            }
        }
        const unsigned b0 = x0, b1 = x1;
        t.r[j] = Rec{b0 + b1, b1, b0 ^ b1 ^ 0x1BD11BDAu, b0};
    }
    return t;
}

__constant__ KTable KTAB = gen_keys();

// ---------- device math (bit-identical to R5) ----------
#if __has_builtin(__builtin_amdgcn_alignbit)
#define ROTL(x, r) __builtin_amdgcn_alignbit((x), (x), 32u - (r))
#define SPLICE(bits) __builtin_amdgcn_alignbit(0x7Fu, (bits), 9u)  // (bits>>9)|0x3f800000
#else
#define ROTL(x, r) __builtin_rotateleft32((x), (r))
#define SPLICE(bits) (((bits) >> 9) | 0x3f800000u)
#endif

struct Consts {
    float P0, P1, P2, P3, P4, P5, P6, P7, P8;   // Giles lo-branch poly
    float NLN2, M25, M3, LO;                    // -ln2, -2.5, -3.0, nextafter(-1,0)
};

__device__ __forceinline__ float poly_lo(float w, const Consts& cc) {
    float p = cc.P0;
    p = fmaf(p, w, cc.P1);
    p = fmaf(p, w, cc.P2);
    p = fmaf(p, w, cc.P3);
    p = fmaf(p, w, cc.P4);
    p = fmaf(p, w, cc.P5);
    p = fmaf(p, w, cc.P6);
    p = fmaf(p, w, cc.P7);
    p = fmaf(p, w, cc.P8);
    return p;
}
__device__ __forceinline__ float poly_hi(float s) {   // rare path
    float p =       -0.000200214257f;
    p = fmaf(p, s,   0.000100950558f);
    p = fmaf(p, s,   0.00134934322f);
    p = fmaf(p, s,  -0.00367342844f);
    p = fmaf(p, s,   0.00573950773f);
    p = fmaf(p, s,  -0.0076224613f);
    p = fmaf(p, s,   0.00943887047f);
    p = fmaf(p, s,   1.00167406f);
    p = fmaf(p, s,   2.83297682f);
    return p;
}

__device__ __forceinline__ unsigned tf_bits(Rec k, unsigned t) {
    unsigned x0 = k.s + t;                 // (k0+k1) + t : round-1 add, mov folded
    unsigned x1 = ROTL(k.b + t, 13) ^ x0;  // finish round 1
#define RND(r) { x0 += x1; x1 = ROTL(x1, r) ^ x0; }
    RND(15) RND(26) RND(6)
    x0 += k.b; x1 += k.c + 1u;
    RND(17) RND(29) RND(16) RND(24)
    x0 += k.c; x1 += k.a + 2u;
    RND(13) RND(15) RND(26) RND(6)
    x0 += k.a; x1 += k.b + 3u;
    RND(17) RND(29) RND(16) RND(24)
    x0 += k.b; x1 += k.c + 4u;
    RND(13) RND(15) RND(26) RND(6)
    x0 += k.c; x1 += k.a + 5u;
#undef RND
    return x0 ^ x1;
}

__device__ __forceinline__ float normal_of_bits(unsigned bits, const Consts& cc) {
    float F = __uint_as_float(SPLICE(bits));            // [1,2)
    float u = fmaf(F, 2.0f, cc.M3);                     // == 2(F-1)+LO (+2^-24)
    u = fmaxf(u, cc.LO);
    float h = fmaf(-u, u, 1.0f);                        // 1 - u^2
    float l2 = __log2f(h);                              // v_log_f32
    float p;
    if (__builtin_expect(__any(l2 <= -7.2134752f), 0)) {   // any lane: w >= 5
        float w  = l2 * cc.NLN2;
        float p1 = poly_lo(w + cc.M25, cc);
        float p2 = poly_hi(sqrtf(w) + cc.M3);
        p = (l2 > -7.2134752f) ? p1 : p2;
    } else {
        p = poly_lo(fmaf(l2, cc.NLN2, cc.M25), cc);     // w - 2.5 in one fma
    }
    return p * u;
}

__device__ __forceinline__ Rec make_key(unsigned j) {
    const unsigned k0 = 0u, k1 = 42u, ks2 = k0 ^ k1 ^ 0x1BD11BDAu;
    unsigned x0 = k0, x1 = j + k1;
#define RND(r) { x0 += x1; x1 = ROTL(x1, r) ^ x0; }
    RND(13) RND(15) RND(26) RND(6)
    x0 += k1;  x1 += ks2 + 1u;
    RND(17) RND(29) RND(16) RND(24)
    x0 += ks2; x1 += k0 + 2u;
    RND(13) RND(15) RND(26) RND(6)
    x0 += k0;  x1 += k1 + 3u;
    RND(17) RND(29) RND(16) RND(24)
    x0 += k1;  x1 += ks2 + 4u;
    RND(13) RND(15) RND(26) RND(6)
    x0 += ks2; x1 += k0 + 5u;
#undef RND
    Rec r; r.s = x0 + x1; r.b = x1; r.c = x0 ^ x1 ^ 0x1BD11BDAu; r.a = x0;
    return r;
}

// fast path valid iff store_every==10, host n_chunks == n_steps/10, keys fit
__device__ __forceinline__ bool fast_ok(int se, int ns, int n_chunks) {
    return se == 10 && n_chunks > 0 && ns / 10 == n_chunks && 10 * n_chunks <= KCAP;
}

// ---------- K1: noise-sum kernel (items = element x chunk-pair) ----------
__global__ __launch_bounds__(256) void langevin_noise(
    const float* __restrict__ gamma_p, const float* __restrict__ kT_p,
    const float* __restrict__ dt_p, const int* __restrict__ nsteps_p,
    const int* __restrict__ store_p, float* __restrict__ out,
    int E, int n_chunks)
{
    if (!fast_ok(*store_p, *nsteps_p, n_chunks)) return;
    const unsigned e = blockIdx.x * 256 + threadIdx.x;
    if ((int)e >= E) return;

    const float g  = gamma_p[0];
    const float kT = kT_p[0];
    const float dt = dt_p[0];
    float scale2 = sqrtf(2.0f * kT * dt / g) * 1.41421356f;
    const float na = -(dt / g);
    const float a  = 1.0f + na;

    Consts cc{2.81022636e-08f,  3.43273939e-07f, -3.5233877e-06f,
             -4.39150654e-06f,  0.00021858087f,  -0.00125372503f,
             -0.00417768164f,   0.246640727f,     1.50140941f,
             -0.69314718f,     -2.5f,            -3.0f, -0.99999994f};
    asm("" : "+v"(cc.P0), "+v"(cc.P1), "+v"(cc.P2), "+v"(cc.P3), "+v"(cc.P4),
             "+v"(cc.P5), "+v"(cc.P6), "+v"(cc.P7), "+v"(cc.P8),
             "+v"(cc.NLN2), "+v"(cc.M25), "+v"(cc.M3), "+v"(cc.LO));

    // w[s] = scale2 * a^(9-s)
    float w[10];
    w[9] = scale2;
#pragma unroll
    for (int s = 8; s >= 0; --s) w[s] = w[s + 1] * a;

    const int c0 = 2 * blockIdx.y;
    const int c1 = c0 + 1;
    const bool has1 = (c1 < n_chunks);

    float S0 = 0.0f, S1 = 0.0f;
#pragma unroll
    for (int s = 0; s < 10; ++s) {
        float z0 = normal_of_bits(tf_bits(KTAB.r[c0 * 10 + s], e), cc);
        S0 = fmaf(w[s], z0, S0);
        if (has1) {
            float z1 = normal_of_bits(tf_bits(KTAB.r[c1 * 10 + s], e), cc);
            S1 = fmaf(w[s], z1, S1);
        }
    }
    out[(size_t)(c0 + 1) * (size_t)E + e] = S0;
    if (has1) out[(size_t)(c1 + 1) * (size_t)E + e] = S1;
}

// ---------- K2: per-element scan (in-place over out) ----------
__global__ __launch_bounds__(256) void langevin_scan(
    const float* __restrict__ x0p,
    const int* __restrict__ nsteps_p, const int* __restrict__ store_p,
    const float* __restrict__ gamma_p, const float* __restrict__ dt_p,
    float* __restrict__ out, int E, int n_chunks)
{
    if (!fast_ok(*store_p, *nsteps_p, n_chunks)) return;
    const unsigned e = blockIdx.x * 256 + threadIdx.x;
    if ((int)e >= E) return;

    const float na = -(dt_p[0] / gamma_p[0]);
    float x = x0p[e];
    out[e] = x;                                   // frame 0
    float* p = out + (size_t)E + e;
#pragma unroll 2
    for (int c = 0; c < n_chunks; ++c) {
        float S = *p;                             // noise sum from K1
#pragma unroll
        for (int s = 0; s < 10; ++s) x = fmaf(na, x, x);   // hom. chain (R5 order)
        x += S;
        *p = x;
        p += (size_t)E;
    }
}

// ---------- KG: generic serial fallback (R5 structure) ----------
__global__ __launch_bounds__(256) void langevin_generic(
    const float* __restrict__ x0p,
    const float* __restrict__ gamma_p, const float* __restrict__ kT_p,
    const float* __restrict__ dt_p, const int* __restrict__ nsteps_p,
    const int* __restrict__ store_p, float* __restrict__ out,
    int E, int n_chunks)
{
    const int ns = *nsteps_p;
    const int se = *store_p;
    if (fast_ok(se, ns, n_chunks)) return;        // fast path owns this config
    const unsigned t = blockIdx.x * 256 + threadIdx.x;
    if ((int)t >= E) return;

    const float g  = gamma_p[0];
    const float kT = kT_p[0];
    const float dt = dt_p[0];
    float scale2 = sqrtf(2.0f * kT * dt / g) * 1.41421356f;
    float na = -(dt / g);

    Consts cc{2.81022636e-08f,  3.43273939e-07f, -3.5233877e-06f,
             -4.39150654e-06f,  0.00021858087f,  -0.00125372503f,
             -0.00417768164f,   0.246640727f,     1.50140941f,
             -0.69314718f,     -2.5f,            -3.0f, -0.99999994f};
    asm("" : "+v"(cc.P0), "+v"(cc.P1), "+v"(cc.P2), "+v"(cc.P3), "+v"(cc.P4),
             "+v"(cc.P5), "+v"(cc.P6), "+v"(cc.P7), "+v"(cc.P8),
             "+v"(cc.NLN2), "+v"(cc.M25), "+v"(cc.M3), "+v"(cc.LO),
             "+v"(scale2), "+v"(na));

    float x = x0p[t];
    out[t] = x;                                   // frame 0
    int frame = 1, since = 0;
#pragma unroll 1
    for (int s = 0; s < ns; ++s) {
        Rec k = (s < KCAP) ? KTAB.r[s] : make_key((unsigned)s);
        float z = normal_of_bits(tf_bits(k, t), cc);
        x = fmaf(scale2, z, fmaf(na, x, x));
        if (++since == se) {
            since = 0;
            if (frame <= n_chunks)
                out[(size_t)frame * (size_t)E + t] = x;
            ++frame;
        }
    }
}

extern "C" void kernel_launch(void* const* d_in, const int* in_sizes, int n_in,
                              void* d_out, int out_size, void* d_ws, size_t ws_size,
                              hipStream_t stream) {
    const float* x0    = (const float*)d_in[0];
    const float* gam   = (const float*)d_in[1];
    const float* kT    = (const float*)d_in[2];
    const float* dt    = (const float*)d_in[3];
    const int*   nst   = (const int*)d_in[4];
    const int*   sev   = (const int*)d_in[5];
    float*       out   = (float*)d_out;

    const int E = in_sizes[0];                    // 100000 * 3 = 300000
    const int eb = (E + 255) / 256;
    int n_chunks = (E > 0) ? (out_size / E - 1) : -1;
    if (n_chunks < 1 || (size_t)(n_chunks + 1) * (size_t)E != (size_t)out_size)
        n_chunks = -1;                            // forces generic path on device

    // KG self-enables iff fast config doesn't hold (device-read values).
    langevin_generic<<<eb, 256, 0, stream>>>(x0, gam, kT, dt, nst, sev, out, E, n_chunks);

    if (n_chunks >= 1) {
        dim3 g1(eb, (n_chunks + 1) / 2);
        langevin_noise<<<g1, 256, 0, stream>>>(gam, kT, dt, nst, sev, out, E, n_chunks);
        langevin_scan<<<eb, 256, 0, stream>>>(x0, nst, sev, gam, dt, out, E, n_chunks);
    }
}

// Round 8
// 643.037 us; speedup vs baseline: 1.1909x; 1.0232x over previous
//
#include <hip/hip_runtime.h>

// Overdamped Langevin (OU), bit-matching JAX partitionable threefry RNG.
// base key (0,42); step key_j = threefry((0,42),(0,j)); per element e at step j:
// bits = b0^b1 of threefry(key_j,(0,e)); u in (-1,1); z = sqrt2*erfinv(u) (Giles);
// x <- x - (dt/g) x + sqrt(2 kT dt/g) z.  Frame 0 = x0, frame c = after c*store_every.
//
// R8: R7's 3-kernel linear-recurrence split (noise-sum K1 / scan K2 / generic KG)
// + K1 packs 2 elements per thread and uses CDNA packed-FP32 (v_pk_fma_f32 /
// v_pk_mul_f32, full-rate VOP3P) for the float transform. The int hash (73 ops,
// no packed 32b-int on CDNA) stays compiler-scheduled intrinsics — R6 showed
// monolithic asm blocks scheduling; single-inst pk asm does not.

#define KCAP 1024  // compile-time key slots (harness n_steps = 1000)

typedef float v2f __attribute__((ext_vector_type(2)));

// ---------- compile-time key table ----------
struct alignas(16) Rec { unsigned s, b, c, a; };  // s=k0+k1, b=k1, c=ks2, a=k0
struct KTable { Rec r[KCAP]; };

constexpr unsigned crotl(unsigned v, int r) { return (v << r) | (v >> (32 - r)); }

constexpr KTable gen_keys() {
    KTable t{};
    for (unsigned j = 0; j < KCAP; ++j) {
        const unsigned k0 = 0u, k1 = 42u, ks2 = k0 ^ k1 ^ 0x1BD11BDAu;
        unsigned x0 = 0u + k0, x1 = j + k1;
        const int rots[20] = {13,15,26,6, 17,29,16,24, 13,15,26,6, 17,29,16,24, 13,15,26,6};
        int ri = 0;
        for (int blk = 0; blk < 5; ++blk) {
            for (int rr = 0; rr < 4; ++rr) { x0 += x1; x1 = crotl(x1, rots[ri++]); x1 ^= x0; }
            switch (blk) {
                case 0: x0 += k1;  x1 += ks2 + 1u; break;
                case 1: x0 += ks2; x1 += k0 + 2u;  break;
                case 2: x0 += k0;  x1 += k1 + 3u;  break;
                case 3: x0 += k1;  x1 += ks2 + 4u; break;
                case 4: x0 += ks2; x1 += k0 + 5u;  break;
            }
        }
        const unsigned b0 = x0, b1 = x1;
        t.r[j] = Rec{b0 + b1, b1, b0 ^ b1 ^ 0x1BD11BDAu, b0};
    }
    return t;
}

__constant__ KTable KTAB = gen_keys();

// ---------- helpers ----------
#if __has_builtin(__builtin_amdgcn_alignbit)
#define ROTL(x, r) __builtin_amdgcn_alignbit((x), (x), 32u - (r))
#define SPLICE(bits) __builtin_amdgcn_alignbit(0x7Fu, (bits), 9u)  // (bits>>9)|0x3f800000
#else
#define ROTL(x, r) __builtin_rotateleft32((x), (r))
#define SPLICE(bits) (((bits) >> 9) | 0x3f800000u)
#endif

__device__ __forceinline__ float dev_log2(float h) {
#if __has_builtin(__builtin_amdgcn_logf)
    return __builtin_amdgcn_logf(h);
#else
    return __log2f(h);
#endif
}

// packed FP32 (VOP3P, full-rate on CDNA): per-half IEEE fma -> bit-exact.
__device__ __forceinline__ v2f pk_fma(v2f a, v2f b, v2f c) {
    v2f d;
    asm("v_pk_fma_f32 %0, %1, %2, %3" : "=v"(d) : "v"(a), "v"(b), "v"(c));
    return d;
}
__device__ __forceinline__ v2f pk_mul(v2f a, v2f b) {
    v2f d;
    asm("v_pk_mul_f32 %0, %1, %2" : "=v"(d) : "v"(a), "v"(b));
    return d;
}

// ---------- threefry hash (compiler-scheduled; 73 VALU ops) ----------
__device__ __forceinline__ unsigned tf_bits(Rec k, unsigned t) {
    unsigned x0 = k.s + t;                 // (k0+k1) + t : round-1 add, mov folded
    unsigned x1 = ROTL(k.b + t, 13) ^ x0;  // finish round 1
#define RND(r) { x0 += x1; x1 = ROTL(x1, r) ^ x0; }
    RND(15) RND(26) RND(6)
    x0 += k.b; x1 += k.c + 1u;
    RND(17) RND(29) RND(16) RND(24)
    x0 += k.c; x1 += k.a + 2u;
    RND(13) RND(15) RND(26) RND(6)
    x0 += k.a; x1 += k.b + 3u;
    RND(17) RND(29) RND(16) RND(24)
    x0 += k.b; x1 += k.c + 4u;
    RND(13) RND(15) RND(26) RND(6)
    x0 += k.c; x1 += k.a + 5u;
#undef RND
    return x0 ^ x1;
}

// ---------- float transform ----------
__device__ __forceinline__ float poly_lo_lit(float w) {   // rare path, literals ok
    float p =        2.81022636e-08f;
    p = fmaf(p, w,   3.43273939e-07f);
    p = fmaf(p, w,  -3.5233877e-06f);
    p = fmaf(p, w,  -4.39150654e-06f);
    p = fmaf(p, w,   0.00021858087f);
    p = fmaf(p, w,  -0.00125372503f);
    p = fmaf(p, w,  -0.00417768164f);
    p = fmaf(p, w,   0.246640727f);
    p = fmaf(p, w,   1.50140941f);
    return p;
}
__device__ __forceinline__ float poly_hi(float s) {
    float p =       -0.000200214257f;
    p = fmaf(p, s,   0.000100950558f);
    p = fmaf(p, s,   0.00134934322f);
    p = fmaf(p, s,  -0.00367342844f);
    p = fmaf(p, s,   0.00573950773f);
    p = fmaf(p, s,  -0.0076224613f);
    p = fmaf(p, s,   0.00943887047f);
    p = fmaf(p, s,   1.00167406f);
    p = fmaf(p, s,   2.83297682f);
    return p;
}
__device__ __forceinline__ float slow_p(float l2) {       // rare (w>=5 in wave)
    float w = l2 * -0.69314718f;
    if (l2 > -7.2134752f) return poly_lo_lit(w - 2.5f);
    return poly_hi(sqrtf(w) - 3.0f);
}

struct PkC { v2f c2, cM3, cNLN2, cM25, P0, P1, P2, P3, P4, P5, P6, P7, P8; };

__device__ __forceinline__ v2f normal2(unsigned bA, unsigned bB, const PkC& pc) {
    v2f F;
    F.x = __uint_as_float(SPLICE(bA));
    F.y = __uint_as_float(SPLICE(bB));
    v2f u = pk_fma(F, pc.c2, pc.cM3);       // 2F-3 == 2(F-1)+LO (+2^-24), per R5
    u.x = fmaxf(u.x, -0.99999994f);
    u.y = fmaxf(u.y, -0.99999994f);
    v2f h;
    h.x = fmaf(-u.x, u.x, 1.0f);            // 1 - u^2, single-rounded
    h.y = fmaf(-u.y, u.y, 1.0f);
    v2f l2;
    l2.x = dev_log2(h.x);
    l2.y = dev_log2(h.y);
    v2f p;
    if (__builtin_expect(__any(fminf(l2.x, l2.y) <= -7.2134752f), 0)) {
        p.x = slow_p(l2.x);
        p.y = slow_p(l2.y);
    } else {
        v2f ww = pk_fma(l2, pc.cNLN2, pc.cM25);   // w - 2.5 single-rounded
        p = pc.P0;
        p = pk_fma(p, ww, pc.P1);
        p = pk_fma(p, ww, pc.P2);
        p = pk_fma(p, ww, pc.P3);
        p = pk_fma(p, ww, pc.P4);
        p = pk_fma(p, ww, pc.P5);
        p = pk_fma(p, ww, pc.P6);
        p = pk_fma(p, ww, pc.P7);
        p = pk_fma(p, ww, pc.P8);
    }
    return pk_mul(p, u);
}

// scalar transform for the generic fallback (bit-identical to R5)
__device__ __forceinline__ float normal_of_bits(unsigned bits) {
    float F = __uint_as_float(SPLICE(bits));
    float u = fmaf(F, 2.0f, -3.0f);
    u = fmaxf(u, -0.99999994f);
    float h = fmaf(-u, u, 1.0f);
    float l2 = dev_log2(h);
    float p;
    if (__builtin_expect(__any(l2 <= -7.2134752f), 0)) {
        p = slow_p(l2);
    } else {
        p = poly_lo_lit(fmaf(l2, -0.69314718f, -2.5f));
    }
    return p * u;
}

__device__ __forceinline__ Rec make_key(unsigned j) {
    const unsigned k0 = 0u, k1 = 42u, ks2 = k0 ^ k1 ^ 0x1BD11BDAu;
    unsigned x0 = k0, x1 = j + k1;
#define RND(r) { x0 += x1; x1 = ROTL(x1, r) ^ x0; }
    RND(13) RND(15) RND(26) RND(6)
    x0 += k1;  x1 += ks2 + 1u;
    RND(17) RND(29) RND(16) RND(24)
    x0 += ks2; x1 += k0 + 2u;
    RND(13) RND(15) RND(26) RND(6)
    x0 += k0;  x1 += k1 + 3u;
    RND(17) RND(29) RND(16) RND(24)
    x0 += k1;  x1 += ks2 + 4u;
    RND(13) RND(15) RND(26) RND(6)
    x0 += ks2; x1 += k0 + 5u;
#undef RND
    Rec r; r.s = x0 + x1; r.b = x1; r.c = x0 ^ x1 ^ 0x1BD11BDAu; r.a = x0;
    return r;
}

__device__ __forceinline__ bool fast_ok(int se, int ns, int n_chunks) {
    return se == 10 && n_chunks > 0 && ns / 10 == n_chunks && 10 * n_chunks <= KCAP;
}

// ---------- K1: noise-sum kernel (2 elements/thread, packed-FP32 transform) ----------
__global__ __launch_bounds__(256) void langevin_noise(
    const float* __restrict__ gamma_p, const float* __restrict__ kT_p,
    const float* __restrict__ dt_p, const int* __restrict__ nsteps_p,
    const int* __restrict__ store_p, float* __restrict__ out,
    int E, int n_chunks)
{
    if (!fast_ok(*store_p, *nsteps_p, n_chunks)) return;
    const unsigned e  = blockIdx.x * 512 + threadIdx.x;
    const unsigned e2 = e + 256;
    if ((int)e >= E) return;
    const bool has2 = ((int)e2 < E);

    const float g  = gamma_p[0];
    const float kT = kT_p[0];
    const float dt = dt_p[0];
    const float scale2 = sqrtf(2.0f * kT * dt / g) * 1.41421356f;
    const float na = -(dt / g);
    const float a  = 1.0f + na;

    // per-step weights w[s] = scale2 * a^(9-s) (R7 order), broadcast to pairs
    float w[10];
    w[9] = scale2;
#pragma unroll
    for (int s = 8; s >= 0; --s) w[s] = w[s + 1] * a;
    v2f wp[10];
#pragma unroll
    for (int s = 0; s < 10; ++s) wp[s] = (v2f){w[s], w[s]};

    PkC pc;
    pc.c2    = (v2f){ 2.0f, 2.0f };
    pc.cM3   = (v2f){-3.0f, -3.0f};
    pc.cNLN2 = (v2f){-0.69314718f, -0.69314718f};
    pc.cM25  = (v2f){-2.5f, -2.5f};
    pc.P0 = (v2f){ 2.81022636e-08f,  2.81022636e-08f};
    pc.P1 = (v2f){ 3.43273939e-07f,  3.43273939e-07f};
    pc.P2 = (v2f){-3.5233877e-06f,  -3.5233877e-06f};
    pc.P3 = (v2f){-4.39150654e-06f, -4.39150654e-06f};
    pc.P4 = (v2f){ 0.00021858087f,   0.00021858087f};
    pc.P5 = (v2f){-0.00125372503f,  -0.00125372503f};
    pc.P6 = (v2f){-0.00417768164f,  -0.00417768164f};
    pc.P7 = (v2f){ 0.246640727f,     0.246640727f};
    pc.P8 = (v2f){ 1.50140941f,      1.50140941f};
    asm("" : "+v"(pc.c2), "+v"(pc.cM3), "+v"(pc.cNLN2), "+v"(pc.cM25),
             "+v"(pc.P0), "+v"(pc.P1), "+v"(pc.P2), "+v"(pc.P3), "+v"(pc.P4),
             "+v"(pc.P5), "+v"(pc.P6), "+v"(pc.P7), "+v"(pc.P8));

    const int c = blockIdx.y;
    const Rec* kr = &KTAB.r[c * 10];

    v2f S = (v2f){0.0f, 0.0f};
#pragma unroll
    for (int s = 0; s < 10; ++s) {
        const Rec k = kr[s];
        unsigned bA = tf_bits(k, e);
        unsigned bB = tf_bits(k, e2);
        v2f z = normal2(bA, bB, pc);
        S = pk_fma(wp[s], z, S);
    }
    float* op = out + (size_t)(c + 1) * (size_t)E;
    op[e] = S.x;
    if (has2) op[e2] = S.y;
}

// ---------- K2: per-element scan (in-place over out) ----------
__global__ __launch_bounds__(256) void langevin_scan(
    const float* __restrict__ x0p,
    const int* __restrict__ nsteps_p, const int* __restrict__ store_p,
    const float* __restrict__ gamma_p, const float* __restrict__ dt_p,
    float* __restrict__ out, int E, int n_chunks)
{
    if (!fast_ok(*store_p, *nsteps_p, n_chunks)) return;
    const unsigned e = blockIdx.x * 256 + threadIdx.x;
    if ((int)e >= E) return;

    const float na = -(dt_p[0] / gamma_p[0]);
    float x = x0p[e];
    out[e] = x;                                   // frame 0
    float* p = out + (size_t)E + e;
#pragma unroll 2
    for (int c = 0; c < n_chunks; ++c) {
        float S = *p;                             // noise sum from K1
#pragma unroll
        for (int s = 0; s < 10; ++s) x = fmaf(na, x, x);   // hom. chain (R5 order)
        x += S;
        *p = x;
        p += (size_t)E;
    }
}

// ---------- KG: generic serial fallback ----------
__global__ __launch_bounds__(256) void langevin_generic(
    const float* __restrict__ x0p,
    const float* __restrict__ gamma_p, const float* __restrict__ kT_p,
    const float* __restrict__ dt_p, const int* __restrict__ nsteps_p,
    const int* __restrict__ store_p, float* __restrict__ out,
    int E, int n_chunks)
{
    const int ns = *nsteps_p;
    const int se = *store_p;
    if (fast_ok(se, ns, n_chunks)) return;        // fast path owns this config
    const unsigned t = blockIdx.x * 256 + threadIdx.x;
    if ((int)t >= E) return;

    const float g  = gamma_p[0];
    const float kT = kT_p[0];
    const float dt = dt_p[0];
    float scale2 = sqrtf(2.0f * kT * dt / g) * 1.41421356f;
    float na = -(dt / g);

    float x = x0p[t];
    out[t] = x;                                   // frame 0
    int frame = 1, since = 0;
#pragma unroll 1
    for (int s = 0; s < ns; ++s) {
        Rec k = (s < KCAP) ? KTAB.r[s] : make_key((unsigned)s);
        float z = normal_of_bits(tf_bits(k, t));
        x = fmaf(scale2, z, fmaf(na, x, x));
        if (++since == se) {
            since = 0;
            if (frame <= n_chunks)
                out[(size_t)frame * (size_t)E + t] = x;
            ++frame;
        }
    }
}

extern "C" void kernel_launch(void* const* d_in, const int* in_sizes, int n_in,
                              void* d_out, int out_size, void* d_ws, size_t ws_size,
                              hipStream_t stream) {
    const float* x0    = (const float*)d_in[0];
    const float* gam   = (const float*)d_in[1];
    const float* kT    = (const float*)d_in[2];
    const float* dt    = (const float*)d_in[3];
    const int*   nst   = (const int*)d_in[4];
    const int*   sev   = (const int*)d_in[5];
    float*       out   = (float*)d_out;

    const int E = in_sizes[0];                    // 100000 * 3 = 300000
    const int eb = (E + 255) / 256;
    int n_chunks = (E > 0) ? (out_size / E - 1) : -1;
    if (n_chunks < 1 || (size_t)(n_chunks + 1) * (size_t)E != (size_t)out_size)
        n_chunks = -1;                            // forces generic path on device

    // KG self-enables iff fast config doesn't hold (device-read values).
    langevin_generic<<<eb, 256, 0, stream>>>(x0, gam, kT, dt, nst, sev, out, E, n_chunks);

    if (n_chunks >= 1) {
        dim3 g1((E + 511) / 512, n_chunks);
        langevin_noise<<<g1, 256, 0, stream>>>(gam, kT, dt, nst, sev, out, E, n_chunks);
        langevin_scan<<<eb, 256, 0, stream>>>(x0, nst, sev, gam, dt, out, E, n_chunks);
    }
}